// Round 10
// baseline (216.251 us; speedup 1.0000x reference)
//
#include <hip/hip_runtime.h>
#include <hip/hip_bf16.h>
#include <stdint.h>

#define BATCH 4096
#define KGRP  8
#define BLK   1024
#define TOTAL 8192

typedef __attribute__((ext_vector_type(8))) short short8;
typedef __attribute__((ext_vector_type(4))) float f32x4;

// ---------- helpers ----------

__device__ __forceinline__ unsigned short f2bf(float f) {
    union { float f; uint32_t u; } c; c.f = f;
    uint32_t u = c.u;
    u += 0x7fffu + ((u >> 16) & 1u);   // round-to-nearest-even
    return (unsigned short)(u >> 16);
}

__device__ __forceinline__ float fast_tanh(float x) {
    float e = __expf(2.0f * x);
    return 1.0f - 2.0f / (e + 1.0f);
}

__device__ __forceinline__ void barrier_tile() {
    asm volatile("s_waitcnt lgkmcnt(0)" ::: "memory");   // ds_write retired before publish
    __builtin_amdgcn_s_barrier();
    __builtin_amdgcn_sched_barrier(0);
}

// ---------- prep: W f32 -> bf16 (48 MB traffic, ~8 us) ----------

__global__ void k_wcast(const float4* __restrict__ W, ushort4* __restrict__ Wb) {
    const int n4 = KGRP * BLK * BLK / 4;
    for (int i = blockIdx.x * 256 + threadIdx.x; i < n4; i += 1024 * 256) {
        float4 f = W[i];
        ushort4 o;
        o.x = f2bf(f.x); o.y = f2bf(f.y); o.z = f2bf(f.z); o.w = f2bf(f.w);
        Wb[i] = o;
    }
}

// ---------- fused GEMM ----------
// Block = 64 rows x 512 cols of one group g. 8 waves, each 64x64 (distinct wc).
// A: v -> reg -> tanh -> bf16 -> swizzled ds_write into A[64][32] dbuf (2x4 KB).
//    (swizzle both sides, verified r4-r9: phys16Bslot = logslot ^ ((row>>1)&3))
// B: straight from global Wb[g] (L2-resident, 2 MB/XCD) as MFMA fragments --
//    each B element read ONCE per block; no LDS, no DMA, no manual vmcnt
//    (all loads compiler-tracked).
// v pipelined 2 tiles ahead in regs (HBM ~900cy > tile ~300cy); B issued at
// tile top, consumed at tile bottom (+4 waves/SIMD TLP).
// One lgkmcnt(0)+s_barrier per tile: A(kt+1) writes go to buf^1 whose readers
// (tile kt-1) passed the previous barrier; reads of buf-cur complete (lgkm,
// in-order) before this tile's barrier.

template<bool ST, bool ISSV, bool LAST>
__device__ __forceinline__ void tile_f(int kt, char* ldsp,
                                       uint32_t aRd, uint32_t aWr,
                                       const float* vsrc, const unsigned short* bsrc,
                                       float4& vCons, float4& vLoad,
                                       f32x4 (*acc)[4]) {
    const uint32_t cur = (uint32_t)(kt & 1) * 4096u;
    const uint32_t oth = cur ^ 4096u;

    // B(kt) fragments: 4 x global 16B (L2); used by MFMA at tile bottom
    short8 bf[4];
#pragma unroll
    for (int nf = 0; nf < 4; ++nf)
        bf[nf] = *(const short8*)(bsrc + (size_t)(nf * 16) * BLK + kt * 32);

    // v(kt+2) into the spare reg pair
    if constexpr (ISSV)
        vLoad = *(const float4*)(vsrc + (kt + 2) * 32);

    // A(kt) fragments from LDS (swizzled)
    short8 am[4];
#pragma unroll
    for (int mf = 0; mf < 4; ++mf)
        am[mf] = *(const short8*)(ldsp + cur + mf * 1024u + aRd);

    // stage A(kt+1): tanh(v regs loaded 2 tiles ago) -> bf16 -> other buf
    if constexpr (ST) {
        ushort4 o;
        o.x = f2bf(fast_tanh(vCons.x));
        o.y = f2bf(fast_tanh(vCons.y));
        o.z = f2bf(fast_tanh(vCons.z));
        o.w = f2bf(fast_tanh(vCons.w));
        *(ushort4*)(ldsp + oth + aWr) = o;
    }

    __builtin_amdgcn_s_setprio(1);
#pragma unroll
    for (int mf = 0; mf < 4; ++mf)
#pragma unroll
        for (int nf = 0; nf < 4; ++nf)
            acc[mf][nf] = __builtin_amdgcn_mfma_f32_16x16x32_bf16(am[mf], bf[nf], acc[mf][nf], 0, 0, 0);
    __builtin_amdgcn_s_setprio(0);

    if constexpr (!LAST) barrier_tile();
}

__global__ __launch_bounds__(512, 4)
void k_main(const float* __restrict__ v, const unsigned short* __restrict__ Wb,
            const float* __restrict__ x, const float* __restrict__ bias,
            float* __restrict__ out) {
    __shared__ __attribute__((aligned(1024))) char lds[43008];  // 2x4K A-bufs + 8x4352 bounce
    char* ldsp = lds;

    const int bid   = blockIdx.x;              // 0..1023
    const int g     = bid & 7;                 // XCD affinity: Wb[g] L2-resident
    const int slot  = bid >> 3;                // 0..127
    const int mtile = slot >> 1;               // 0..63  (64-row panels)
    const int ntile = slot & 1;                // 0..1   (512-col halves)
    const int gout  = (g + 1) & 7;

    const int tid  = threadIdx.x;
    const int lane = tid & 63;
    const int w    = tid >> 6;                 // 0..7 == wc

    // A ds_read: row = mf*16 + (lane&15), log slot = lane>>4; phys slot ^= (row>>1)&3
    const uint32_t aRd = (uint32_t)(lane & 15) * 64u +
                         (((uint32_t)((lane >> 4) ^ ((lane >> 1) & 3))) << 4);
    // A ds_write: thread t -> row t>>3, elem cols (t&7)*4 (8 bytes)
    const int wrow = tid >> 3;                 // 0..63
    const int h    = tid & 7;                  // 0..7
    const uint32_t aWr = (uint32_t)wrow * 64u +
                         (((uint32_t)(((h >> 1) ^ ((wrow >> 1) & 3)))) << 4) +
                         (uint32_t)(h & 1) * 8u;
    // v source for staging (per-thread): + kt*32
    const float* vsrc = v + (size_t)(mtile * 64 + wrow) * TOTAL + (size_t)g * BLK + h * 4;
    // B source (per-lane): row = col index of W, + nf*16*BLK + kt*32
    const unsigned short* bsrc = Wb + ((size_t)g * BLK + ntile * 512 + w * 64 + (lane & 15)) * BLK
                                    + (lane >> 4) * 8;

    f32x4 acc[4][4];
#pragma unroll
    for (int m = 0; m < 4; ++m)
#pragma unroll
        for (int n = 0; n < 4; ++n) acc[m][n] = (f32x4){0.f, 0.f, 0.f, 0.f};

    // prologue: stage A(0) into buf0; preload v(1)
    {
        float4 f0 = *(const float4*)(vsrc);
        ushort4 o;
        o.x = f2bf(fast_tanh(f0.x));
        o.y = f2bf(fast_tanh(f0.y));
        o.z = f2bf(fast_tanh(f0.z));
        o.w = f2bf(fast_tanh(f0.w));
        *(ushort4*)(ldsp + aWr) = o;
    }
    float4 vA = *(const float4*)(vsrc + 32);   // v(1), consumed at kt=0
    float4 vB;
    barrier_tile();

    // K loop: 32 tiles, 2 per iteration (buf parity + vA/vB reg pipeline)
#pragma unroll 1
    for (int k2 = 0; k2 < 15; ++k2) {
        const int kt = k2 * 2;
        tile_f<true, true, false>(kt,     ldsp, aRd, aWr, vsrc, bsrc, vA, vB, acc);
        tile_f<true, true, false>(kt + 1, ldsp, aRd, aWr, vsrc, bsrc, vB, vA, acc);
    }
    tile_f<true,  false, false>(30, ldsp, aRd, aWr, vsrc, bsrc, vA, vB, acc);  // stage A(31)
    tile_f<false, false, true >(31, ldsp, aRd, aWr, vsrc, bsrc, vB, vA, acc);  // no stage

    // ---------------- epilogue: out = x + bias + acc (r7/r9-verified bounce) ----
    // acc C/D mapping (m89/m91): col = lane&15, row = (lane>>4)*4 + j.
    // Bounce region (8192..43008) disjoint from K-loop bufs -> no barrier needed.
    const int q  = lane >> 4;
    const int cl = lane & 15;
    const int col0 = ntile * 512 + w * 64;     // within group
    char* eb = ldsp + 8192u + (uint32_t)w * 4352u;
    const float4 bias4 = *(const float4*)&bias[g * BLK + col0 + cl * 4];

#pragma unroll
    for (int m = 0; m < 4; ++m) {
#pragma unroll
        for (int n = 0; n < 4; ++n)
#pragma unroll
            for (int j = 0; j < 4; ++j)
                *(float*)(eb + (q * 4 + j) * 272 + (n * 16 + cl) * 4) = acc[m][n][j];
        asm volatile("s_waitcnt lgkmcnt(0)" ::: "memory");
        __builtin_amdgcn_sched_barrier(0);
#pragma unroll
        for (int i = 0; i < 4; ++i) {
            f32x4 vv = *(const f32x4*)(eb + (q + 4 * i) * 272 + cl * 16);
            const int r = mtile * 64 + m * 16 + q + 4 * i;
            const size_t idx = (size_t)r * TOTAL + (size_t)gout * BLK + col0 + cl * 4;
            const float4 xv = *(const float4*)&x[idx];
            float4 o;
            o.x = xv.x + bias4.x + vv[0];
            o.y = xv.y + bias4.y + vv[1];
            o.z = xv.z + bias4.z + vv[2];
            o.w = xv.w + bias4.w + vv[3];
            *(float4*)&out[idx] = o;
        }
        asm volatile("s_waitcnt lgkmcnt(0)" ::: "memory");
        __builtin_amdgcn_sched_barrier(0);
    }
}

// ---------- fallback (ws too small): correct but slow ----------

__global__ void k_naive(const float* __restrict__ x, const float* __restrict__ v,
                        const float* __restrict__ W, const float* __restrict__ b,
                        float* __restrict__ out) {
    __shared__ float hv[BLK];
    const int bid = blockIdx.x;
    const int quarter = bid & 3;
    const int g = (bid >> 2) & 7;
    const int row = bid >> 5;
    for (int i = threadIdx.x; i < BLK; i += 256)
        hv[i] = tanhf(v[(size_t)row * TOTAL + g * BLK + i]);
    __syncthreads();
    const int o = quarter * 256 + threadIdx.x;
    const float* wrow = W + ((size_t)g * BLK + o) * BLK;
    float s = 0.f;
    for (int i = 0; i < BLK; ++i) s += hv[i] * wrow[i];
    const size_t oi = (size_t)row * TOTAL + (size_t)((g + 1) & 7) * BLK + o;
    out[oi] = x[oi] + b[g * BLK + o] + s;
}

// ---------- launch ----------

extern "C" void kernel_launch(void* const* d_in, const int* in_sizes, int n_in,
                              void* d_out, int out_size, void* d_ws, size_t ws_size,
                              hipStream_t stream) {
    const float* x = (const float*)d_in[0];
    const float* v = (const float*)d_in[1];
    const float* W = (const float*)d_in[2];
    const float* b = (const float*)d_in[3];
    float* out = (float*)d_out;

    const size_t needW = (size_t)KGRP * BLK * BLK * sizeof(unsigned short);   // 16 MB

    if (ws_size >= needW) {
        unsigned short* Wb = (unsigned short*)d_ws;
        k_wcast<<<1024, 256, 0, stream>>>((const float4*)W, (ushort4*)Wb);
        k_main<<<1024, 512, 0, stream>>>(v, Wb, x, b, out);
    } else {
        k_naive<<<BATCH * KGRP * 4, 256, 0, stream>>>(x, v, W, b, out);
    }
}

// Round 11
// 174.454 us; speedup vs baseline: 1.2396x; 1.2396x over previous
//
#include <hip/hip_runtime.h>
#include <hip/hip_bf16.h>
#include <stdint.h>

#define BATCH 4096
#define KGRP  8
#define BLK   1024
#define TOTAL 8192

typedef __attribute__((ext_vector_type(8))) short short8;
typedef __attribute__((ext_vector_type(4))) float f32x4;

// ---------- helpers ----------

__device__ __forceinline__ unsigned short f2bf(float f) {
    union { float f; uint32_t u; } c; c.f = f;
    uint32_t u = c.u;
    u += 0x7fffu + ((u >> 16) & 1u);   // round-to-nearest-even
    return (unsigned short)(u >> 16);
}

__device__ __forceinline__ float fast_tanh(float x) {
    float e = __expf(2.0f * x);
    return 1.0f - 2.0f / (e + 1.0f);
}

// ---------- pass 1: pack A and B into MFMA-fragment-major layout ----------
// Fragment element mapping (verified r1-r9 via LDS path): lane l holds
// [row = l&15][k = (l>>4)*8 .. +8). A 1 KB chunk = one wave-fragment, so the
// GEMM's loads are base + lane*16 -> single coalesced 1 KB transaction.
//
// Hf (64 MB): chunk index c = (((g*64 + m)*32 + kt)*4 + mf)*64 + lane
//   element: tanh(v[m*64 + mf*16 + (l&15)][g*1024 + kt*32 + (l>>4)*8 + j])
// Wbf (16 MB): c = (((g*16 + n64)*32 + kt)*4 + nf)*64 + lane
//   element: W[g][n64*64 + nf*16 + (l&15)][kt*32 + (l>>4)*8 + j]
// Reads: lanes {b,16+b,32+b,48+b} cover one 128B line of a row -> line-efficient.
// Writes: consecutive threads -> consecutive 16B -> fully coalesced.

__global__ void k_pack(const float* __restrict__ v, const float* __restrict__ W,
                       short8* __restrict__ Hf, short8* __restrict__ Wbf) {
    const int bid = blockIdx.x;
    if (bid < 16384) {
        const uint32_t c = (uint32_t)bid * 256u + threadIdx.x;   // 0 .. 4M
        const uint32_t lane = c & 63u;
        const uint32_t mf   = (c >> 6) & 3u;
        const uint32_t kt   = (c >> 8) & 31u;
        const uint32_t m    = (c >> 13) & 63u;
        const uint32_t g    = c >> 19;
        const int r  = (int)(m * 64 + mf * 16 + (lane & 15u));
        const int kc = (int)(kt * 32 + (lane >> 4) * 8u);
        const float* s = v + (size_t)r * TOTAL + g * BLK + kc;
        const float4 f0 = *(const float4*)s;
        const float4 f1 = *(const float4*)(s + 4);
        short8 o;
        o[0] = (short)f2bf(fast_tanh(f0.x)); o[1] = (short)f2bf(fast_tanh(f0.y));
        o[2] = (short)f2bf(fast_tanh(f0.z)); o[3] = (short)f2bf(fast_tanh(f0.w));
        o[4] = (short)f2bf(fast_tanh(f1.x)); o[5] = (short)f2bf(fast_tanh(f1.y));
        o[6] = (short)f2bf(fast_tanh(f1.z)); o[7] = (short)f2bf(fast_tanh(f1.w));
        Hf[c] = o;
    } else {
        const uint32_t c = (uint32_t)(bid - 16384) * 256u + threadIdx.x;   // 0 .. 1M
        const uint32_t lane = c & 63u;
        const uint32_t nf   = (c >> 6) & 3u;
        const uint32_t kt   = (c >> 8) & 31u;
        const uint32_t n64  = (c >> 13) & 15u;
        const uint32_t g    = c >> 17;
        const int orow = (int)(n64 * 64 + nf * 16 + (lane & 15u));
        const int kc   = (int)(kt * 32 + (lane >> 4) * 8u);
        const float* s = W + ((size_t)g * BLK + orow) * BLK + kc;
        const float4 f0 = *(const float4*)s;
        const float4 f1 = *(const float4*)(s + 4);
        short8 o;
        o[0] = (short)f2bf(f0.x); o[1] = (short)f2bf(f0.y);
        o[2] = (short)f2bf(f0.z); o[3] = (short)f2bf(f0.w);
        o[4] = (short)f2bf(f1.x); o[5] = (short)f2bf(f1.y);
        o[6] = (short)f2bf(f1.z); o[7] = (short)f2bf(f1.w);
        Wbf[c] = o;
    }
}

// ---------- pass 2: GEMM with NO LDS in the K-loop ----------
// 2048 blocks x 256 thr (4 waves). Wave = 64x64 output tile. All frag loads are
// coalesced 1 KB from L2/L3-resident packed buffers; frags double-buffered in
// registers; compiler-tracked vmcnt; NO barriers, NO LDS, waves fully async
// (inter-wave TLP hides L2 latency). Epilogue = r7/r9-verified LDS bounce.

#define LDFRAGS(dst, base, kt)                                              \
    _Pragma("unroll")                                                       \
    for (int _f = 0; _f < 4; ++_f)                                          \
        dst[_f] = *(const short8*)((base) + (size_t)(kt) * 4096 + _f * 1024);

#define MFMA16(acc, a, b)                                                   \
    __builtin_amdgcn_s_setprio(1);                                          \
    _Pragma("unroll")                                                       \
    for (int _mf = 0; _mf < 4; ++_mf)                                       \
        _Pragma("unroll")                                                   \
        for (int _nf = 0; _nf < 4; ++_nf)                                   \
            acc[_mf][_nf] = __builtin_amdgcn_mfma_f32_16x16x32_bf16(        \
                a[_mf], b[_nf], acc[_mf][_nf], 0, 0, 0);                    \
    __builtin_amdgcn_s_setprio(0);

__global__ __launch_bounds__(256, 3)
void k_main(const short8* __restrict__ Hf, const short8* __restrict__ Wbf,
            const float* __restrict__ x, const float* __restrict__ bias,
            float* __restrict__ out) {
    __shared__ __attribute__((aligned(64))) char ebounce[4 * 4352];

    const int bid  = blockIdx.x;               // 0..2047
    const int g    = bid & 7;                  // XCD affinity (Wbf[g] = 2MB, L2-resident)
    const int rest = bid >> 3;                 // 0..255
    const int pm   = rest >> 2;                // 0..63   64-row panel
    const int nblk = rest & 3;                 // 0..3    256-col panel
    const int gout = (g + 1) & 7;

    const int tid  = threadIdx.x;
    const int lane = tid & 63;
    const int w    = tid >> 6;                 // 0..3
    const int n64  = nblk * 4 + w;             // 0..15   wave's 64-col panel

    const char* Ab = (const char*)Hf  + ((size_t)(g * 64 + pm)  * 128) * 1024 + (size_t)lane * 16;
    const char* Bb = (const char*)Wbf + ((size_t)(g * 16 + n64) * 128) * 1024 + (size_t)lane * 16;

    f32x4 acc[4][4];
#pragma unroll
    for (int m = 0; m < 4; ++m)
#pragma unroll
        for (int n = 0; n < 4; ++n) acc[m][n] = (f32x4){0.f, 0.f, 0.f, 0.f};

    short8 aX[4], bX[4], aY[4], bY[4];
    LDFRAGS(aX, Ab, 0); LDFRAGS(bX, Bb, 0);

#pragma unroll 1
    for (int k2 = 0; k2 < 15; ++k2) {
        LDFRAGS(aY, Ab, 2 * k2 + 1); LDFRAGS(bY, Bb, 2 * k2 + 1);
        MFMA16(acc, aX, bX);
        LDFRAGS(aX, Ab, 2 * k2 + 2); LDFRAGS(bX, Bb, 2 * k2 + 2);
        MFMA16(acc, aY, bY);
    }
    LDFRAGS(aY, Ab, 31); LDFRAGS(bY, Bb, 31);
    MFMA16(acc, aX, bX);
    MFMA16(acc, aY, bY);

    // ---------------- epilogue: out = x + bias + acc (r7/r9-verified bounce) ----
    // acc C/D mapping (m89/m91): col = lane&15, row = (lane>>4)*4 + j.
    const int q  = lane >> 4;
    const int cl = lane & 15;
    const int row0  = pm * 64;
    const int col0g = n64 * 64;                // within group
    char* eb = ebounce + (uint32_t)w * 4352u;
    const float4 bias4 = *(const float4*)&bias[g * BLK + col0g + cl * 4];

#pragma unroll
    for (int m = 0; m < 4; ++m) {
#pragma unroll
        for (int n = 0; n < 4; ++n)
#pragma unroll
            for (int j = 0; j < 4; ++j)
                *(float*)(eb + (q * 4 + j) * 272 + (n * 16 + cl) * 4) = acc[m][n][j];
        asm volatile("s_waitcnt lgkmcnt(0)" ::: "memory");
        __builtin_amdgcn_sched_barrier(0);
#pragma unroll
        for (int i = 0; i < 4; ++i) {
            f32x4 vv = *(const f32x4*)(eb + (q + 4 * i) * 272 + cl * 16);
            const int r = row0 + m * 16 + q + 4 * i;
            const size_t idx = (size_t)r * TOTAL + (size_t)gout * BLK + col0g + cl * 4;
            const float4 xv = *(const float4*)&x[idx];
            float4 o;
            o.x = xv.x + bias4.x + vv[0];
            o.y = xv.y + bias4.y + vv[1];
            o.z = xv.z + bias4.z + vv[2];
            o.w = xv.w + bias4.w + vv[3];
            *(float4*)&out[idx] = o;
        }
        asm volatile("s_waitcnt lgkmcnt(0)" ::: "memory");
        __builtin_amdgcn_sched_barrier(0);
    }
}

// ---------- fallback (ws too small): correct but slow ----------

__global__ void k_naive(const float* __restrict__ x, const float* __restrict__ v,
                        const float* __restrict__ W, const float* __restrict__ b,
                        float* __restrict__ out) {
    __shared__ float hv[BLK];
    const int bid = blockIdx.x;
    const int quarter = bid & 3;
    const int g = (bid >> 2) & 7;
    const int row = bid >> 5;
    for (int i = threadIdx.x; i < BLK; i += 256)
        hv[i] = tanhf(v[(size_t)row * TOTAL + g * BLK + i]);
    __syncthreads();
    const int o = quarter * 256 + threadIdx.x;
    const float* wrow = W + ((size_t)g * BLK + o) * BLK;
    float s = 0.f;
    for (int i = 0; i < BLK; ++i) s += hv[i] * wrow[i];
    const size_t oi = (size_t)row * TOTAL + (size_t)((g + 1) & 7) * BLK + o;
    out[oi] = x[oi] + b[g * BLK + o] + s;
}

// ---------- launch ----------

extern "C" void kernel_launch(void* const* d_in, const int* in_sizes, int n_in,
                              void* d_out, int out_size, void* d_ws, size_t ws_size,
                              hipStream_t stream) {
    const float* x = (const float*)d_in[0];
    const float* v = (const float*)d_in[1];
    const float* W = (const float*)d_in[2];
    const float* b = (const float*)d_in[3];
    float* out = (float*)d_out;

    const size_t needH = (size_t)BATCH * TOTAL * sizeof(unsigned short);      // 64 MB
    const size_t needW = (size_t)KGRP * BLK * BLK * sizeof(unsigned short);   // 16 MB

    if (ws_size >= needH + needW) {
        short8* Hf  = (short8*)d_ws;
        short8* Wbf = (short8*)((char*)d_ws + needH);
        k_pack<<<20480, 256, 0, stream>>>(v, W, Hf, Wbf);
        k_main<<<2048, 256, 0, stream>>>(Hf, Wbf, x, b, out);
    } else {
        k_naive<<<BATCH * KGRP * 4, 256, 0, stream>>>(x, v, W, b, out);
    }
}